// Round 1
// baseline (690.212 us; speedup 1.0000x reference)
//
#include <hip/hip_runtime.h>

#define TOKENS 16384
#define INF 2048
#define OUTF 2048
#define NGROUP 32   // INF/64
#define RANK 32
#define BM 128
#define BN 128

typedef int   int32x4  __attribute__((ext_vector_type(4)));
typedef float floatx4  __attribute__((ext_vector_type(4)));
typedef short bf16x8   __attribute__((ext_vector_type(8)));

typedef __attribute__((address_space(1))) const void gconst_t;
typedef __attribute__((address_space(3))) void ldsv_t;

__device__ __forceinline__ void gload_lds16(const void* g, void* l) {
  __builtin_amdgcn_global_load_lds((gconst_t*)g, (ldsv_t*)l, 16, 0, 0);
}

__device__ __forceinline__ unsigned short f2bf(float f) {
  unsigned u = __float_as_uint(f);
  unsigned r = (u + 0x7FFFu + ((u >> 16) & 1u)) >> 16;
  return (unsigned short)r;
}

// ---------------- kernel 1: unpack int4 weights to int8 ----------------
// qweight arrives as int32 per element (harness int rule), one packed byte each.
__device__ __forceinline__ unsigned unp2(int e0, int e1) {
  int l0 = ((int)((unsigned)e0 << 28)) >> 28;
  int h0 = ((int)((unsigned)e0 << 24)) >> 28;
  int l1 = ((int)((unsigned)e1 << 28)) >> 28;
  int h1 = ((int)((unsigned)e1 << 24)) >> 28;
  return (l0 & 0xFF) | ((h0 & 0xFF) << 8) | ((l1 & 0xFF) << 16) | ((h1 & 0xFF) << 24);
}

__global__ __launch_bounds__(256) void unpack_kernel(const int* __restrict__ qw,
                                                     signed char* __restrict__ wq8) {
  int idx = blockIdx.x * 256 + threadIdx.x;     // 262144 threads, 8 packed bytes each
  const int4* src = (const int4*)qw;
  int4 v0 = src[idx * 2 + 0];
  int4 v1 = src[idx * 2 + 1];
  int4 out;
  out.x = (int)unp2(v0.x, v0.y);
  out.y = (int)unp2(v0.z, v0.w);
  out.z = (int)unp2(v1.x, v1.y);
  out.w = (int)unp2(v1.z, v1.w);
  *(int4*)(wq8 + (size_t)idx * 16) = out;
}

// ---------------- kernel 2: activation smoothing + int4 quant + down-proj ----------------
__global__ __launch_bounds__(256) void quant_kernel(
    const float* __restrict__ x, const float* __restrict__ smooth,
    const float* __restrict__ pd, signed char* __restrict__ qx8,
    float* __restrict__ ascales, float* __restrict__ tdown) {
  int lane = threadIdx.x & 63;
  int t = blockIdx.x * 4 + (threadIdx.x >> 6);   // one wave per token
  const float* xrow = x + (size_t)t * INF + lane * 32;
  const float* srow = smooth + lane * 32;

  float xs[32];
  float amax = 0.f;
#pragma unroll
  for (int j = 0; j < 32; j += 4) {
    float4 xv = *(const float4*)(xrow + j);
    float4 sv = *(const float4*)(srow + j);
    xs[j + 0] = xv.x / sv.x;
    xs[j + 1] = xv.y / sv.y;
    xs[j + 2] = xv.z / sv.z;
    xs[j + 3] = xv.w / sv.w;
    amax = fmaxf(amax, fmaxf(fmaxf(fabsf(xs[j]), fabsf(xs[j + 1])),
                             fmaxf(fabsf(xs[j + 2]), fabsf(xs[j + 3]))));
  }
  // group of 64 channels = lane pair (lane i owns 32 consecutive channels)
  float gmax = fmaxf(amax, __shfl_xor(amax, 1, 64));
  float ascale = gmax > 0.f ? gmax / 7.0f : 1.0f;
  float rq = 1.0f / ascale;
  if (!(lane & 1)) ascales[(size_t)t * NGROUP + (lane >> 1)] = ascale;

  signed char* qrow = qx8 + (size_t)t * INF + lane * 32;
#pragma unroll
  for (int j = 0; j < 32; j += 16) {
    unsigned w[4];
#pragma unroll
    for (int q = 0; q < 4; ++q) {
      unsigned pk = 0;
#pragma unroll
      for (int b = 0; b < 4; ++b) {
        float qf = rintf(xs[j + q * 4 + b] * rq);
        qf = fminf(7.f, fmaxf(-8.f, qf));
        int qi = (int)qf;
        pk |= ((unsigned)(qi & 0xFF)) << (8 * b);
      }
      w[q] = pk;
    }
    int4 st; st.x = (int)w[0]; st.y = (int)w[1]; st.z = (int)w[2]; st.w = (int)w[3];
    *(int4*)(qrow + j) = st;
  }

  // down-projection: tdown[t][r] = sum_c xs[c] * pd[c][r]
  float part[32];
#pragma unroll
  for (int r = 0; r < 32; ++r) part[r] = 0.f;
  const float* pdrow = pd + (size_t)lane * 32 * RANK;
#pragma unroll
  for (int j = 0; j < 32; ++j) {
    float xv = xs[j];
#pragma unroll
    for (int q = 0; q < 8; ++q) {
      float4 p = *(const float4*)(pdrow + j * RANK + q * 4);
      part[q * 4 + 0] += xv * p.x;
      part[q * 4 + 1] += xv * p.y;
      part[q * 4 + 2] += xv * p.z;
      part[q * 4 + 3] += xv * p.w;
    }
  }
#pragma unroll
  for (int m = 1; m < 64; m <<= 1) {
#pragma unroll
    for (int r = 0; r < 32; ++r) part[r] += __shfl_xor(part[r], m, 64);
  }
  if (lane == 0) {
    float* td = tdown + (size_t)t * RANK;
#pragma unroll
    for (int r = 0; r < 32; ++r) td[r] = part[r];
  }
}

// ---------------- kernel 3: int8 MFMA GEMM + fused low-rank + bias ----------------
__global__ __launch_bounds__(256, 2) void gemm_kernel(
    const signed char* __restrict__ qx8, const signed char* __restrict__ wq8,
    const float* __restrict__ ascales, const float* __restrict__ wscales,
    const float* __restrict__ tdown, const float* __restrict__ pu,
    const float* __restrict__ bias, float* __restrict__ y) {
  __shared__ char smem[65536];
  signed char* a_lds = (signed char*)smem;             // [2][128*64] int8
  signed char* b_lds = (signed char*)(smem + 16384);   // [2][128*64] int8
  float* as_t = (float*)(smem + 32768);                // [32][128]
  float* ws_t = (float*)(smem + 49152);                // [32][128]

  int tid = threadIdx.x;
  int lane = tid & 63;
  int wid = tid >> 6;
  int wr = wid >> 1, wc = wid & 1;                     // wave tile 64x64
  int o0 = blockIdx.x * BN;
  int t0 = blockIdx.y * BM;

  // stage scale tiles (once per block)
  {
    int tt = tid >> 1, h = (tid & 1) * 16;
    const float* src = ascales + (size_t)(t0 + tt) * NGROUP + h;
#pragma unroll
    for (int q = 0; q < 4; ++q) {
      float4 v = *(const float4*)(src + q * 4);
      as_t[(h + q * 4 + 0) * BM + tt] = v.x;
      as_t[(h + q * 4 + 1) * BM + tt] = v.y;
      as_t[(h + q * 4 + 2) * BM + tt] = v.z;
      as_t[(h + q * 4 + 3) * BM + tt] = v.w;
    }
    int gg = tid >> 3, cc = (tid & 7) * 16;
    const float* src2 = wscales + (size_t)gg * OUTF + o0 + cc;
#pragma unroll
    for (int q = 0; q < 4; ++q)
      *(float4*)&ws_t[gg * BN + cc + q * 4] = *(const float4*)(src2 + q * 4);
  }

  float acc[4][4][4];
#pragma unroll
  for (int m = 0; m < 4; ++m)
#pragma unroll
    for (int n = 0; n < 4; ++n)
#pragma unroll
      for (int r = 0; r < 4; ++r) acc[m][n][r] = 0.f;

  auto stage = [&](int buf, int g) {
#pragma unroll
    for (int i = 0; i < 2; ++i) {
      int c = tid + i * 256;                            // chunk: row=c>>2, 16B slot=c&3
      const signed char* ga = qx8 + (size_t)(t0 + (c >> 2)) * INF + g * 64 + (c & 3) * 16;
      gload_lds16(ga, a_lds + buf * 8192 + (wid + i * 4) * 1024);
      const signed char* gb = wq8 + (size_t)(o0 + (c >> 2)) * INF + g * 64 + (c & 3) * 16;
      gload_lds16(gb, b_lds + buf * 8192 + (wid + i * 4) * 1024);
    }
  };

  stage(0, 0);
  __syncthreads();

  for (int g = 0; g < NGROUP; ++g) {
    int buf = g & 1;
    if (g + 1 < NGROUP) stage(buf ^ 1, g + 1);

    int koff = (lane >> 4) << 4;                        // 16-byte k-chunk per 16-lane group
    int32x4 af[4], bf_[4];
#pragma unroll
    for (int m = 0; m < 4; ++m)
      af[m] = *(const int32x4*)(a_lds + buf * 8192 +
                                ((wr << 6) + (m << 4) + (lane & 15)) * 64 + koff);
#pragma unroll
    for (int n = 0; n < 4; ++n)
      bf_[n] = *(const int32x4*)(b_lds + buf * 8192 +
                                 ((wc << 6) + (n << 4) + (lane & 15)) * 64 + koff);

    float asv[4][4];
#pragma unroll
    for (int m = 0; m < 4; ++m) {
      floatx4 v = *(const floatx4*)&as_t[g * BM + (wr << 6) + (m << 4) + ((lane >> 4) << 2)];
      asv[m][0] = v[0]; asv[m][1] = v[1]; asv[m][2] = v[2]; asv[m][3] = v[3];
    }
    float wsv[4];
#pragma unroll
    for (int n = 0; n < 4; ++n) wsv[n] = ws_t[g * BN + (wc << 6) + (n << 4) + (lane & 15)];

#pragma unroll
    for (int m = 0; m < 4; ++m)
#pragma unroll
      for (int n = 0; n < 4; ++n) {
        int32x4 zero = {0, 0, 0, 0};
        int32x4 d = __builtin_amdgcn_mfma_i32_16x16x64_i8(af[m], bf_[n], zero, 0, 0, 0);
#pragma unroll
        for (int r = 0; r < 4; ++r)
          acc[m][n][r] += (float)d[r] * (asv[m][r] * wsv[n]);
      }
    __syncthreads();
  }

  // epilogue: low-rank via one bf16 MFMA pass (K = RANK = 32) + bias
  unsigned short* td_lds = (unsigned short*)smem;          // [128][32] bf16
  unsigned short* pu_lds = (unsigned short*)(smem + 8192); // [128][32] bf16
  {
    int row = tid >> 1, h = (tid & 1) * 16;
    const float* ts = tdown + (size_t)(t0 + row) * RANK + h;
    const float* ps = pu + (size_t)(o0 + row) * RANK + h;
    unsigned tw[8], pw[8];
#pragma unroll
    for (int q = 0; q < 4; ++q) {
      float4 v = *(const float4*)(ts + q * 4);
      tw[q * 2 + 0] = (unsigned)f2bf(v.x) | ((unsigned)f2bf(v.y) << 16);
      tw[q * 2 + 1] = (unsigned)f2bf(v.z) | ((unsigned)f2bf(v.w) << 16);
      float4 p = *(const float4*)(ps + q * 4);
      pw[q * 2 + 0] = (unsigned)f2bf(p.x) | ((unsigned)f2bf(p.y) << 16);
      pw[q * 2 + 1] = (unsigned)f2bf(p.z) | ((unsigned)f2bf(p.w) << 16);
    }
    int4 s0, s1;
    s0.x = (int)tw[0]; s0.y = (int)tw[1]; s0.z = (int)tw[2]; s0.w = (int)tw[3];
    s1.x = (int)tw[4]; s1.y = (int)tw[5]; s1.z = (int)tw[6]; s1.w = (int)tw[7];
    *(int4*)(td_lds + row * 32 + h) = s0;
    *(int4*)(td_lds + row * 32 + h + 8) = s1;
    s0.x = (int)pw[0]; s0.y = (int)pw[1]; s0.z = (int)pw[2]; s0.w = (int)pw[3];
    s1.x = (int)pw[4]; s1.y = (int)pw[5]; s1.z = (int)pw[6]; s1.w = (int)pw[7];
    *(int4*)(pu_lds + row * 32 + h) = s0;
    *(int4*)(pu_lds + row * 32 + h + 8) = s1;
  }
  __syncthreads();

  bf16x8 ta[4], pb4[4];
  int koff8 = (lane >> 4) << 3;
#pragma unroll
  for (int m = 0; m < 4; ++m)
    ta[m] = *(const bf16x8*)&td_lds[((wr << 6) + (m << 4) + (lane & 15)) * 32 + koff8];
#pragma unroll
  for (int n = 0; n < 4; ++n)
    pb4[n] = *(const bf16x8*)&pu_lds[((wc << 6) + (n << 4) + (lane & 15)) * 32 + koff8];

#pragma unroll
  for (int n = 0; n < 4; ++n) {
    int oc = o0 + (wc << 6) + (n << 4) + (lane & 15);
    float bv = bias[oc];
#pragma unroll
    for (int m = 0; m < 4; ++m) {
      floatx4 c;
      c[0] = acc[m][n][0]; c[1] = acc[m][n][1]; c[2] = acc[m][n][2]; c[3] = acc[m][n][3];
      c = __builtin_amdgcn_mfma_f32_16x16x32_bf16(ta[m], pb4[n], c, 0, 0, 0);
#pragma unroll
      for (int r = 0; r < 4; ++r) {
        int tr = t0 + (wr << 6) + (m << 4) + ((lane >> 4) << 2) + r;
        y[(size_t)tr * OUTF + oc] = c[r] + bv;
      }
    }
  }
}

extern "C" void kernel_launch(void* const* d_in, const int* in_sizes, int n_in,
                              void* d_out, int out_size, void* d_ws, size_t ws_size,
                              hipStream_t stream) {
  const float* x      = (const float*)d_in[0];
  const int*   qw     = (const int*)d_in[1];
  const float* wsc    = (const float*)d_in[2];
  const float* smooth = (const float*)d_in[3];
  const float* bias   = (const float*)d_in[4];
  const float* pd     = (const float*)d_in[5];
  const float* pu     = (const float*)d_in[6];
  float* y = (float*)d_out;

  char* ws = (char*)d_ws;
  signed char* qx8 = (signed char*)ws;                          // 33554432 B
  signed char* wq8 = (signed char*)(ws + 33554432);             //  4194304 B
  float* ascales   = (float*)(ws + 33554432 + 4194304);         //  2097152 B
  float* tdown     = (float*)(ws + 33554432 + 4194304 + 2097152); // 2097152 B

  unpack_kernel<<<1024, 256, 0, stream>>>(qw, wq8);
  quant_kernel<<<TOKENS / 4, 256, 0, stream>>>(x, smooth, pd, qx8, ascales, tdown);
  gemm_kernel<<<dim3(OUTF / BN, TOKENS / BM), 256, 0, stream>>>(
      qx8, wq8, ascales, wsc, tdown, pu, bias, y);
}

// Round 2
// 209.825 us; speedup vs baseline: 3.2895x; 3.2895x over previous
//
#include <hip/hip_runtime.h>

#define TOKENS 16384
#define INF 2048
#define OUTF 2048
#define NGROUP 32   // INF/64
#define RANK 32
#define BM 128
#define BN 128

typedef int   int32x4  __attribute__((ext_vector_type(4)));
typedef int   int32x2  __attribute__((ext_vector_type(2)));
typedef float floatx4  __attribute__((ext_vector_type(4)));
typedef short bf16x8   __attribute__((ext_vector_type(8)));

typedef __attribute__((address_space(1))) const void gconst_t;
typedef __attribute__((address_space(3))) void ldsv_t;

__device__ __forceinline__ void gload_lds16(const void* g, void* l) {
  __builtin_amdgcn_global_load_lds((gconst_t*)g, (ldsv_t*)l, 16, 0, 0);
}

__device__ __forceinline__ unsigned short f2bf(float f) {
  unsigned u = __float_as_uint(f);
  unsigned r = (u + 0x7FFFu + ((u >> 16) & 1u)) >> 16;
  return (unsigned short)r;
}

// ---------------- kernel 1: unpack int4 weights to int8 ----------------
__device__ __forceinline__ unsigned unp2(int e0, int e1) {
  int l0 = ((int)((unsigned)e0 << 28)) >> 28;
  int h0 = ((int)((unsigned)e0 << 24)) >> 28;
  int l1 = ((int)((unsigned)e1 << 28)) >> 28;
  int h1 = ((int)((unsigned)e1 << 24)) >> 28;
  return (l0 & 0xFF) | ((h0 & 0xFF) << 8) | ((l1 & 0xFF) << 16) | ((h1 & 0xFF) << 24);
}

__global__ __launch_bounds__(256) void unpack_kernel(const int* __restrict__ qw,
                                                     signed char* __restrict__ wq8) {
  int idx = blockIdx.x * 256 + threadIdx.x;
  const int4* src = (const int4*)qw;
  int4 v0 = src[idx * 2 + 0];
  int4 v1 = src[idx * 2 + 1];
  int4 out;
  out.x = (int)unp2(v0.x, v0.y);
  out.y = (int)unp2(v0.z, v0.w);
  out.z = (int)unp2(v1.x, v1.y);
  out.w = (int)unp2(v1.z, v1.w);
  *(int4*)(wq8 + (size_t)idx * 16) = out;
}

// ---------------- kernel 1b: pd [2048][32] f32 -> pdT [32][2048] bf16 ----------------
__global__ __launch_bounds__(256) void prep_pdT(const float* __restrict__ pd,
                                                unsigned short* __restrict__ pdT) {
  int idx = blockIdx.x * 256 + threadIdx.x;   // 65536 elements
  int r = idx >> 11, c = idx & 2047;
  pdT[idx] = f2bf(pd[(size_t)c * RANK + r]);
}

// ---------------- kernel 2: coalesced quant + MFMA down-projection ----------------
// block: 256 thr / 4 waves / 32 tokens; 8 channel-chunks of 256.
__global__ __launch_bounds__(256) void quant_kernel(
    const float* __restrict__ x, const float* __restrict__ smooth,
    const unsigned short* __restrict__ pdT,
    signed char* __restrict__ qx8, float* __restrict__ ascales,
    float* __restrict__ tdown) {
  __shared__ char lds[32768];   // xs [32][256] bf16 swz @0, pdT chunk [32][256] bf16 swz @16384
  int tid = threadIdx.x, lane = tid & 63, wid = tid >> 6;
  int t0 = blockIdx.x * 32;
  int mi = wid >> 1, ni = wid & 1;
  floatx4 acc = {0.f, 0.f, 0.f, 0.f};

  floatx4 xv[8];
  floatx4 sm;
  int32x4 pv[4];

  auto issue_loads = [&](int kc) {
    const float* xb = x + (size_t)(t0 + wid * 8) * INF + kc * 256 + lane * 4;
#pragma unroll
    for (int r = 0; r < 8; ++r) xv[r] = *(const floatx4*)(xb + r * INF);
    sm = *(const floatx4*)(smooth + kc * 256 + lane * 4);
#pragma unroll
    for (int q = 0; q < 4; ++q) {
      int flat = tid + q * 256;                 // 16B unit of pdT chunk (1024 total)
      int row = flat >> 5, c16 = flat & 31;
      pv[q] = *(const int32x4*)((const char*)pdT + (size_t)row * 4096 + kc * 512 + c16 * 16);
    }
  };

  issue_loads(0);

  for (int kc = 0; kc < 8; ++kc) {
    // ---- write phase: pdT chunk + quant + xs->LDS ----
    floatx4 rsm;
    rsm[0] = 1.0f / sm[0]; rsm[1] = 1.0f / sm[1];
    rsm[2] = 1.0f / sm[2]; rsm[3] = 1.0f / sm[3];
#pragma unroll
    for (int q = 0; q < 4; ++q) {
      int flat = tid + q * 256;
      int row = flat >> 5, c16 = flat & 31;
      int byte = (row * 512 + c16 * 16) ^ ((row & 7) << 4);
      *(int32x4*)(lds + 16384 + byte) = pv[q];
    }
#pragma unroll
    for (int r = 0; r < 8; ++r) {
      floatx4 xs;
      xs[0] = xv[r][0] * rsm[0]; xs[1] = xv[r][1] * rsm[1];
      xs[2] = xv[r][2] * rsm[2]; xs[3] = xv[r][3] * rsm[3];
      float m4 = fmaxf(fmaxf(fabsf(xs[0]), fabsf(xs[1])),
                       fmaxf(fabsf(xs[2]), fabsf(xs[3])));
      m4 = fmaxf(m4, __shfl_xor(m4, 1, 64));
      m4 = fmaxf(m4, __shfl_xor(m4, 2, 64));
      m4 = fmaxf(m4, __shfl_xor(m4, 4, 64));
      m4 = fmaxf(m4, __shfl_xor(m4, 8, 64));   // 16-lane span = one group of 64 channels
      float ascale = m4 > 0.f ? m4 / 7.0f : 1.0f;
      float rq = 1.0f / ascale;
      int tok = t0 + wid * 8 + r;
      if ((lane & 15) == 0)
        ascales[(size_t)tok * NGROUP + kc * 4 + (lane >> 4)] = ascale;
      int pk = 0;
#pragma unroll
      for (int b = 0; b < 4; ++b) {
        float qf = fminf(7.f, fmaxf(-8.f, rintf(xs[b] * rq)));
        pk |= ((int)qf & 0xFF) << (8 * b);
      }
      *(int*)(qx8 + (size_t)tok * INF + kc * 256 + lane * 4) = pk;
      unsigned lo = (unsigned)f2bf(xs[0]) | ((unsigned)f2bf(xs[1]) << 16);
      unsigned hi = (unsigned)f2bf(xs[2]) | ((unsigned)f2bf(xs[3]) << 16);
      int lrow = wid * 8 + r;
      int xbyte = (lrow * 512 + lane * 8) ^ ((lrow & 7) << 4);
      int32x2 wv; wv[0] = (int)lo; wv[1] = (int)hi;
      *(int32x2*)(lds + xbyte) = wv;
    }
    __syncthreads();
    if (kc + 1 < 8) issue_loads(kc + 1);       // prefetch under MFMA
    // ---- MFMA phase: tdown += xs_chunk @ pd_chunk ----
#pragma unroll
    for (int ks = 0; ks < 8; ++ks) {
      int arow = mi * 16 + (lane & 15);
      int ab = (arow * 512 + ks * 64 + ((lane >> 4) << 4)) ^ ((arow & 7) << 4);
      bf16x8 av = *(const bf16x8*)(lds + ab);
      int brow = ni * 16 + (lane & 15);
      int bb = (brow * 512 + ks * 64 + ((lane >> 4) << 4)) ^ ((brow & 7) << 4);
      bf16x8 bv = *(const bf16x8*)(lds + 16384 + bb);
      acc = __builtin_amdgcn_mfma_f32_16x16x32_bf16(av, bv, acc, 0, 0, 0);
    }
    __syncthreads();
  }

  int trow = t0 + mi * 16 + ((lane >> 4) << 2);
  int col = ni * 16 + (lane & 15);
#pragma unroll
  for (int r = 0; r < 4; ++r)
    tdown[(size_t)(trow + r) * RANK + col] = acc[r];
}

// ---------------- kernel 3: int8 MFMA GEMM + fused low-rank + bias ----------------
__global__ __launch_bounds__(256, 2) void gemm_kernel(
    const signed char* __restrict__ qx8, const signed char* __restrict__ wq8,
    const float* __restrict__ ascales, const float* __restrict__ wscales,
    const float* __restrict__ tdown, const float* __restrict__ pu,
    const float* __restrict__ bias, float* __restrict__ y) {
  __shared__ char smem[65536];
  signed char* a_lds = (signed char*)smem;             // [2][128*64] int8
  signed char* b_lds = (signed char*)(smem + 16384);   // [2][128*64] int8
  float* as_t = (float*)(smem + 32768);                // [32][128]
  float* ws_t = (float*)(smem + 49152);                // [32][128]

  int tid = threadIdx.x;
  int lane = tid & 63;
  int wid = tid >> 6;
  int wr = wid >> 1, wc = wid & 1;                     // wave tile 64x64
  int o0 = blockIdx.x * BN;
  int t0 = blockIdx.y * BM;

  {
    int tt = tid >> 1, h = (tid & 1) * 16;
    const float* src = ascales + (size_t)(t0 + tt) * NGROUP + h;
#pragma unroll
    for (int q = 0; q < 4; ++q) {
      float4 v = *(const float4*)(src + q * 4);
      as_t[(h + q * 4 + 0) * BM + tt] = v.x;
      as_t[(h + q * 4 + 1) * BM + tt] = v.y;
      as_t[(h + q * 4 + 2) * BM + tt] = v.z;
      as_t[(h + q * 4 + 3) * BM + tt] = v.w;
    }
    int gg = tid >> 3, cc = (tid & 7) * 16;
    const float* src2 = wscales + (size_t)gg * OUTF + o0 + cc;
#pragma unroll
    for (int q = 0; q < 4; ++q)
      *(float4*)&ws_t[gg * BN + cc + q * 4] = *(const float4*)(src2 + q * 4);
  }

  float acc[4][4][4];
#pragma unroll
  for (int m = 0; m < 4; ++m)
#pragma unroll
    for (int n = 0; n < 4; ++n)
#pragma unroll
      for (int r = 0; r < 4; ++r) acc[m][n][r] = 0.f;

  auto stage = [&](int buf, int g) {
#pragma unroll
    for (int i = 0; i < 2; ++i) {
      int c = tid + i * 256;
      const signed char* ga = qx8 + (size_t)(t0 + (c >> 2)) * INF + g * 64 + (c & 3) * 16;
      gload_lds16(ga, a_lds + buf * 8192 + (wid + i * 4) * 1024);
      const signed char* gb = wq8 + (size_t)(o0 + (c >> 2)) * INF + g * 64 + (c & 3) * 16;
      gload_lds16(gb, b_lds + buf * 8192 + (wid + i * 4) * 1024);
    }
  };

  stage(0, 0);
  __syncthreads();

  for (int g = 0; g < NGROUP; ++g) {
    int buf = g & 1;
    if (g + 1 < NGROUP) stage(buf ^ 1, g + 1);

    int koff = (lane >> 4) << 4;
    int32x4 af[4], bf_[4];
#pragma unroll
    for (int m = 0; m < 4; ++m)
      af[m] = *(const int32x4*)(a_lds + buf * 8192 +
                                ((wr << 6) + (m << 4) + (lane & 15)) * 64 + koff);
#pragma unroll
    for (int n = 0; n < 4; ++n)
      bf_[n] = *(const int32x4*)(b_lds + buf * 8192 +
                                 ((wc << 6) + (n << 4) + (lane & 15)) * 64 + koff);

    float asv[4][4];
#pragma unroll
    for (int m = 0; m < 4; ++m) {
      floatx4 v = *(const floatx4*)&as_t[g * BM + (wr << 6) + (m << 4) + ((lane >> 4) << 2)];
      asv[m][0] = v[0]; asv[m][1] = v[1]; asv[m][2] = v[2]; asv[m][3] = v[3];
    }
    float wsv[4];
#pragma unroll
    for (int n = 0; n < 4; ++n) wsv[n] = ws_t[g * BN + (wc << 6) + (n << 4) + (lane & 15)];

#pragma unroll
    for (int m = 0; m < 4; ++m)
#pragma unroll
      for (int n = 0; n < 4; ++n) {
        int32x4 zero = {0, 0, 0, 0};
        int32x4 d = __builtin_amdgcn_mfma_i32_16x16x64_i8(af[m], bf_[n], zero, 0, 0, 0);
#pragma unroll
        for (int r = 0; r < 4; ++r)
          acc[m][n][r] += (float)d[r] * (asv[m][r] * wsv[n]);
      }
    __syncthreads();
  }

  // epilogue: low-rank via one bf16 MFMA pass (K = RANK = 32) + bias
  unsigned short* td_lds = (unsigned short*)smem;          // [128][32] bf16
  unsigned short* pu_lds = (unsigned short*)(smem + 8192); // [128][32] bf16
  {
    int row = tid >> 1, h = (tid & 1) * 16;
    const float* ts = tdown + (size_t)(t0 + row) * RANK + h;
    const float* ps = pu + (size_t)(o0 + row) * RANK + h;
    unsigned tw[8], pw[8];
#pragma unroll
    for (int q = 0; q < 4; ++q) {
      float4 v = *(const float4*)(ts + q * 4);
      tw[q * 2 + 0] = (unsigned)f2bf(v.x) | ((unsigned)f2bf(v.y) << 16);
      tw[q * 2 + 1] = (unsigned)f2bf(v.z) | ((unsigned)f2bf(v.w) << 16);
      float4 p = *(const float4*)(ps + q * 4);
      pw[q * 2 + 0] = (unsigned)f2bf(p.x) | ((unsigned)f2bf(p.y) << 16);
      pw[q * 2 + 1] = (unsigned)f2bf(p.z) | ((unsigned)f2bf(p.w) << 16);
    }
    int4 s0, s1;
    s0.x = (int)tw[0]; s0.y = (int)tw[1]; s0.z = (int)tw[2]; s0.w = (int)tw[3];
    s1.x = (int)tw[4]; s1.y = (int)tw[5]; s1.z = (int)tw[6]; s1.w = (int)tw[7];
    *(int4*)(td_lds + row * 32 + h) = s0;
    *(int4*)(td_lds + row * 32 + h + 8) = s1;
    s0.x = (int)pw[0]; s0.y = (int)pw[1]; s0.z = (int)pw[2]; s0.w = (int)pw[3];
    s1.x = (int)pw[4]; s1.y = (int)pw[5]; s1.z = (int)pw[6]; s1.w = (int)pw[7];
    *(int4*)(pu_lds + row * 32 + h) = s0;
    *(int4*)(pu_lds + row * 32 + h + 8) = s1;
  }
  __syncthreads();

  bf16x8 ta[4], pb4[4];
  int koff8 = (lane >> 4) << 3;
#pragma unroll
  for (int m = 0; m < 4; ++m)
    ta[m] = *(const bf16x8*)&td_lds[((wr << 6) + (m << 4) + (lane & 15)) * 32 + koff8];
#pragma unroll
  for (int n = 0; n < 4; ++n)
    pb4[n] = *(const bf16x8*)&pu_lds[((wc << 6) + (n << 4) + (lane & 15)) * 32 + koff8];

#pragma unroll
  for (int n = 0; n < 4; ++n) {
    int oc = o0 + (wc << 6) + (n << 4) + (lane & 15);
    float bv = bias[oc];
#pragma unroll
    for (int m = 0; m < 4; ++m) {
      floatx4 c;
      c[0] = acc[m][n][0]; c[1] = acc[m][n][1]; c[2] = acc[m][n][2]; c[3] = acc[m][n][3];
      c = __builtin_amdgcn_mfma_f32_16x16x32_bf16(ta[m], pb4[n], c, 0, 0, 0);
#pragma unroll
      for (int r = 0; r < 4; ++r) {
        int tr = t0 + (wr << 6) + (m << 4) + ((lane >> 4) << 2) + r;
        y[(size_t)tr * OUTF + oc] = c[r] + bv;
      }
    }
  }
}

extern "C" void kernel_launch(void* const* d_in, const int* in_sizes, int n_in,
                              void* d_out, int out_size, void* d_ws, size_t ws_size,
                              hipStream_t stream) {
  const float* x      = (const float*)d_in[0];
  const int*   qw     = (const int*)d_in[1];
  const float* wsc    = (const float*)d_in[2];
  const float* smooth = (const float*)d_in[3];
  const float* bias   = (const float*)d_in[4];
  const float* pd     = (const float*)d_in[5];
  const float* pu     = (const float*)d_in[6];
  float* y = (float*)d_out;

  char* ws = (char*)d_ws;
  signed char* qx8 = (signed char*)ws;                            // 33554432 B
  signed char* wq8 = (signed char*)(ws + 33554432);               //  4194304 B
  float* ascales   = (float*)(ws + 33554432 + 4194304);           //  2097152 B
  float* tdown     = (float*)(ws + 33554432 + 4194304 + 2097152); //  2097152 B
  // pdT bf16 scratch lives in the tail of d_out (128 KB at offset 64 MB);
  // it is consumed by quant_kernel and later fully overwritten by gemm_kernel's y stores.
  unsigned short* pdT = (unsigned short*)((char*)d_out + (64u << 20));

  unpack_kernel<<<1024, 256, 0, stream>>>(qw, wq8);
  prep_pdT<<<256, 256, 0, stream>>>(pd, pdT);
  quant_kernel<<<TOKENS / 32, 256, 0, stream>>>(x, smooth, pdT, qx8, ascales, tdown);
  gemm_kernel<<<dim3(OUTF / BN, TOKENS / BM), 256, 0, stream>>>(
      qx8, wq8, ascales, wsc, tdown, pu, bias, y);
}

// Round 3
// 206.591 us; speedup vs baseline: 3.3410x; 1.0157x over previous
//
#include <hip/hip_runtime.h>

#define TOKENS 16384
#define INF 2048
#define OUTF 2048
#define NGROUP 32   // INF/64
#define RANK 32
#define BM 128
#define BN 128

typedef int   int32x4  __attribute__((ext_vector_type(4)));
typedef int   int32x2  __attribute__((ext_vector_type(2)));
typedef float floatx4  __attribute__((ext_vector_type(4)));
typedef short bf16x8   __attribute__((ext_vector_type(8)));

typedef __attribute__((address_space(1))) const void gconst_t;
typedef __attribute__((address_space(3))) void ldsv_t;

__device__ __forceinline__ void gload_lds16(const void* g, void* l) {
  __builtin_amdgcn_global_load_lds((gconst_t*)g, (ldsv_t*)l, 16, 0, 0);
}

__device__ __forceinline__ unsigned short f2bf(float f) {
  unsigned u = __float_as_uint(f);
  unsigned r = (u + 0x7FFFu + ((u >> 16) & 1u)) >> 16;
  return (unsigned short)r;
}

// ---------------- kernel 1: unpack int4 weights to int8 ----------------
__device__ __forceinline__ unsigned unp2(int e0, int e1) {
  int l0 = ((int)((unsigned)e0 << 28)) >> 28;
  int h0 = ((int)((unsigned)e0 << 24)) >> 28;
  int l1 = ((int)((unsigned)e1 << 28)) >> 28;
  int h1 = ((int)((unsigned)e1 << 24)) >> 28;
  return (l0 & 0xFF) | ((h0 & 0xFF) << 8) | ((l1 & 0xFF) << 16) | ((h1 & 0xFF) << 24);
}

__global__ __launch_bounds__(256) void unpack_kernel(const int* __restrict__ qw,
                                                     signed char* __restrict__ wq8) {
  int idx = blockIdx.x * 256 + threadIdx.x;
  const int4* src = (const int4*)qw;
  int4 v0 = src[idx * 2 + 0];
  int4 v1 = src[idx * 2 + 1];
  int4 out;
  out.x = (int)unp2(v0.x, v0.y);
  out.y = (int)unp2(v0.z, v0.w);
  out.z = (int)unp2(v1.x, v1.y);
  out.w = (int)unp2(v1.z, v1.w);
  *(int4*)(wq8 + (size_t)idx * 16) = out;
}

// ---------------- kernel 1b: pd [2048][32] f32 -> pdT [32][2048] bf16 ----------------
__global__ __launch_bounds__(256) void prep_pdT(const float* __restrict__ pd,
                                                unsigned short* __restrict__ pdT) {
  int idx = blockIdx.x * 256 + threadIdx.x;   // 65536 elements
  int r = idx >> 11, c = idx & 2047;
  pdT[idx] = f2bf(pd[(size_t)c * RANK + r]);
}

// ---------------- kernel 2: coalesced quant + MFMA down-projection ----------------
__global__ __launch_bounds__(256) void quant_kernel(
    const float* __restrict__ x, const float* __restrict__ smooth,
    const unsigned short* __restrict__ pdT,
    signed char* __restrict__ qx8, float* __restrict__ ascales,
    float* __restrict__ tdown) {
  __shared__ char lds[32768];   // xs [32][256] bf16 swz @0, pdT chunk [32][256] bf16 swz @16384
  int tid = threadIdx.x, lane = tid & 63, wid = tid >> 6;
  int t0 = blockIdx.x * 32;
  int mi = wid >> 1, ni = wid & 1;
  floatx4 acc = {0.f, 0.f, 0.f, 0.f};

  floatx4 xv[8];
  floatx4 sm;
  int32x4 pv[4];

  auto issue_loads = [&](int kc) {
    const float* xb = x + (size_t)(t0 + wid * 8) * INF + kc * 256 + lane * 4;
#pragma unroll
    for (int r = 0; r < 8; ++r) xv[r] = *(const floatx4*)(xb + r * INF);
    sm = *(const floatx4*)(smooth + kc * 256 + lane * 4);
#pragma unroll
    for (int q = 0; q < 4; ++q) {
      int flat = tid + q * 256;                 // 16B unit of pdT chunk (1024 total)
      int row = flat >> 5, c16 = flat & 31;
      pv[q] = *(const int32x4*)((const char*)pdT + (size_t)row * 4096 + kc * 512 + c16 * 16);
    }
  };

  issue_loads(0);

  for (int kc = 0; kc < 8; ++kc) {
    floatx4 rsm;
    rsm[0] = 1.0f / sm[0]; rsm[1] = 1.0f / sm[1];
    rsm[2] = 1.0f / sm[2]; rsm[3] = 1.0f / sm[3];
#pragma unroll
    for (int q = 0; q < 4; ++q) {
      int flat = tid + q * 256;
      int row = flat >> 5, c16 = flat & 31;
      int byte = (row * 512 + c16 * 16) ^ ((row & 7) << 4);
      *(int32x4*)(lds + 16384 + byte) = pv[q];
    }
#pragma unroll
    for (int r = 0; r < 8; ++r) {
      floatx4 xs;
      xs[0] = xv[r][0] * rsm[0]; xs[1] = xv[r][1] * rsm[1];
      xs[2] = xv[r][2] * rsm[2]; xs[3] = xv[r][3] * rsm[3];
      float m4 = fmaxf(fmaxf(fabsf(xs[0]), fabsf(xs[1])),
                       fmaxf(fabsf(xs[2]), fabsf(xs[3])));
      m4 = fmaxf(m4, __shfl_xor(m4, 1, 64));
      m4 = fmaxf(m4, __shfl_xor(m4, 2, 64));
      m4 = fmaxf(m4, __shfl_xor(m4, 4, 64));
      m4 = fmaxf(m4, __shfl_xor(m4, 8, 64));
      float ascale = m4 > 0.f ? m4 / 7.0f : 1.0f;
      float rq = 1.0f / ascale;
      int tok = t0 + wid * 8 + r;
      if ((lane & 15) == 0)
        ascales[(size_t)tok * NGROUP + kc * 4 + (lane >> 4)] = ascale;
      int pk = 0;
#pragma unroll
      for (int b = 0; b < 4; ++b) {
        float qf = fminf(7.f, fmaxf(-8.f, rintf(xs[b] * rq)));
        pk |= ((int)qf & 0xFF) << (8 * b);
      }
      *(int*)(qx8 + (size_t)tok * INF + kc * 256 + lane * 4) = pk;
      unsigned lo = (unsigned)f2bf(xs[0]) | ((unsigned)f2bf(xs[1]) << 16);
      unsigned hi = (unsigned)f2bf(xs[2]) | ((unsigned)f2bf(xs[3]) << 16);
      int lrow = wid * 8 + r;
      int xbyte = (lrow * 512 + lane * 8) ^ ((lrow & 7) << 4);
      int32x2 wv; wv[0] = (int)lo; wv[1] = (int)hi;
      *(int32x2*)(lds + xbyte) = wv;
    }
    __syncthreads();
    if (kc + 1 < 8) issue_loads(kc + 1);
#pragma unroll
    for (int ks = 0; ks < 8; ++ks) {
      int arow = mi * 16 + (lane & 15);
      int ab = (arow * 512 + ks * 64 + ((lane >> 4) << 4)) ^ ((arow & 7) << 4);
      bf16x8 av = *(const bf16x8*)(lds + ab);
      int brow = ni * 16 + (lane & 15);
      int bb = (brow * 512 + ks * 64 + ((lane >> 4) << 4)) ^ ((brow & 7) << 4);
      bf16x8 bv = *(const bf16x8*)(lds + 16384 + bb);
      acc = __builtin_amdgcn_mfma_f32_16x16x32_bf16(av, bv, acc, 0, 0, 0);
    }
    __syncthreads();
  }

  int trow = t0 + mi * 16 + ((lane >> 4) << 2);
  int col = ni * 16 + (lane & 15);
#pragma unroll
  for (int r = 0; r < 4; ++r)
    tdown[(size_t)(trow + r) * RANK + col] = acc[r];
}

// ---------------- kernel 3: int8 MFMA GEMM, counted-vmcnt 3-buf pipeline ----------------
// LDS map: buf b at smem + b*16384  (A [128][64B swz] @+0, B @+8192), b=0..2
//          as_t f32[32][128] @49152, ws_t f32[32][128] @65536   (total 81920)
__global__ __launch_bounds__(256, 2) void gemm_kernel(
    const signed char* __restrict__ qx8, const signed char* __restrict__ wq8,
    const float* __restrict__ ascales, const float* __restrict__ wscales,
    const float* __restrict__ tdown, const float* __restrict__ pu,
    const float* __restrict__ bias, float* __restrict__ y) {
  __shared__ char smem[81920];
  float* as_t = (float*)(smem + 49152);
  float* ws_t = (float*)(smem + 65536);

  int tid = threadIdx.x;
  int lane = tid & 63;
  int wid = tid >> 6;
  int wr = wid >> 1, wc = wid & 1;                     // wave tile 64x64
  int o0 = blockIdx.x * BN;
  int t0 = blockIdx.y * BM;

  // stage scale tiles (once per block)
  {
    int tt = tid >> 1, h = (tid & 1) * 16;
    const float* src = ascales + (size_t)(t0 + tt) * NGROUP + h;
#pragma unroll
    for (int q = 0; q < 4; ++q) {
      float4 v = *(const float4*)(src + q * 4);
      as_t[(h + q * 4 + 0) * BM + tt] = v.x;
      as_t[(h + q * 4 + 1) * BM + tt] = v.y;
      as_t[(h + q * 4 + 2) * BM + tt] = v.z;
      as_t[(h + q * 4 + 3) * BM + tt] = v.w;
    }
    int gg = tid >> 3, cc = (tid & 7) * 16;
    const float* src2 = wscales + (size_t)gg * OUTF + o0 + cc;
#pragma unroll
    for (int q = 0; q < 4; ++q)
      *(float4*)&ws_t[gg * BN + cc + q * 4] = *(const float4*)(src2 + q * 4);
  }

  float acc[4][4][4];
#pragma unroll
  for (int m = 0; m < 4; ++m)
#pragma unroll
    for (int n = 0; n < 4; ++n)
#pragma unroll
      for (int r = 0; r < 4; ++r) acc[m][n][r] = 0.f;

  // staging: 4 global_load_lds per call; source pre-swizzled (slot ^= (row>>1)&3)
  // so linear LDS write + swizzled read are the same involution (rule #21).
  auto stage = [&](int g) {
    int bufb = (g % 3) * 16384;
#pragma unroll
    for (int i = 0; i < 2; ++i) {
      int c = tid + i * 256;
      int row = c >> 2;
      int l = (c & 3) ^ ((row >> 1) & 3);
      gload_lds16(qx8 + (size_t)(t0 + row) * INF + g * 64 + l * 16,
                  smem + bufb + (wid + i * 4) * 1024);
      gload_lds16(wq8 + (size_t)(o0 + row) * INF + g * 64 + l * 16,
                  smem + bufb + 8192 + (wid + i * 4) * 1024);
    }
  };

  // per-lane fragment byte offsets (swizzled), hoisted
  int aoff[4], boff[4];
#pragma unroll
  for (int m = 0; m < 4; ++m) {
    int arow = (wr << 6) + (m << 4) + (lane & 15);
    aoff[m] = arow * 64 + ((((lane >> 4)) ^ ((arow >> 1) & 3)) << 4);
    int brow = (wc << 6) + (m << 4) + (lane & 15);
    boff[m] = 8192 + brow * 64 + ((((lane >> 4)) ^ ((brow >> 1) & 3)) << 4);
  }
  int asoff = (wr << 6) + ((lane >> 4) << 2);
  int wsoff = (wc << 6) + (lane & 15);

  __syncthreads();          // scale tiles visible
  stage(0);
  stage(1);

  for (int g = 0; g < NGROUP; ++g) {
    // counted wait: buf g's 4 loads done, buf g+1's stay in flight across the barrier
    if (g == NGROUP - 1) asm volatile("s_waitcnt vmcnt(0)" ::: "memory");
    else                 asm volatile("s_waitcnt vmcnt(4)" ::: "memory");
    __builtin_amdgcn_s_barrier();
    __builtin_amdgcn_sched_barrier(0);

    if (g + 2 < NGROUP) stage(g + 2);   // issue early, hides under compute

    int bufb = (g % 3) * 16384;
    int32x4 af[4], bf_[4];
#pragma unroll
    for (int m = 0; m < 4; ++m) af[m] = *(const int32x4*)(smem + bufb + aoff[m]);
#pragma unroll
    for (int n = 0; n < 4; ++n) bf_[n] = *(const int32x4*)(smem + bufb + boff[n]);

    float asv[4][4];
#pragma unroll
    for (int m = 0; m < 4; ++m) {
      floatx4 v = *(const floatx4*)&as_t[g * BM + asoff + (m << 4)];
      asv[m][0] = v[0]; asv[m][1] = v[1]; asv[m][2] = v[2]; asv[m][3] = v[3];
    }
    float wsv[4];
#pragma unroll
    for (int n = 0; n < 4; ++n) wsv[n] = ws_t[g * BN + wsoff + (n << 4)];

    __builtin_amdgcn_s_setprio(1);
#pragma unroll
    for (int m = 0; m < 4; ++m)
#pragma unroll
      for (int n = 0; n < 4; ++n) {
        int32x4 zero = {0, 0, 0, 0};
        int32x4 d = __builtin_amdgcn_mfma_i32_16x16x64_i8(af[m], bf_[n], zero, 0, 0, 0);
#pragma unroll
        for (int r = 0; r < 4; ++r)
          acc[m][n][r] += ((float)d[r] * wsv[n]) * asv[m][r];
      }
    __builtin_amdgcn_s_setprio(0);
  }

  __syncthreads();   // full sync before reusing smem for epilogue

  // epilogue: low-rank via one bf16 MFMA pass (K = RANK = 32) + bias
  unsigned short* td_lds = (unsigned short*)smem;          // [128][32] bf16
  unsigned short* pu_lds = (unsigned short*)(smem + 8192); // [128][32] bf16
  {
    int row = tid >> 1, h = (tid & 1) * 16;
    const float* ts = tdown + (size_t)(t0 + row) * RANK + h;
    const float* ps = pu + (size_t)(o0 + row) * RANK + h;
    unsigned tw[8], pw[8];
#pragma unroll
    for (int q = 0; q < 4; ++q) {
      float4 v = *(const float4*)(ts + q * 4);
      tw[q * 2 + 0] = (unsigned)f2bf(v.x) | ((unsigned)f2bf(v.y) << 16);
      tw[q * 2 + 1] = (unsigned)f2bf(v.z) | ((unsigned)f2bf(v.w) << 16);
      float4 p = *(const float4*)(ps + q * 4);
      pw[q * 2 + 0] = (unsigned)f2bf(p.x) | ((unsigned)f2bf(p.y) << 16);
      pw[q * 2 + 1] = (unsigned)f2bf(p.z) | ((unsigned)f2bf(p.w) << 16);
    }
    int4 s0, s1;
    s0.x = (int)tw[0]; s0.y = (int)tw[1]; s0.z = (int)tw[2]; s0.w = (int)tw[3];
    s1.x = (int)tw[4]; s1.y = (int)tw[5]; s1.z = (int)tw[6]; s1.w = (int)tw[7];
    *(int4*)(td_lds + row * 32 + h) = s0;
    *(int4*)(td_lds + row * 32 + h + 8) = s1;
    s0.x = (int)pw[0]; s0.y = (int)pw[1]; s0.z = (int)pw[2]; s0.w = (int)pw[3];
    s1.x = (int)pw[4]; s1.y = (int)pw[5]; s1.z = (int)pw[6]; s1.w = (int)pw[7];
    *(int4*)(pu_lds + row * 32 + h) = s0;
    *(int4*)(pu_lds + row * 32 + h + 8) = s1;
  }
  __syncthreads();

  bf16x8 ta[4], pb4[4];
  int koff8 = (lane >> 4) << 3;
#pragma unroll
  for (int m = 0; m < 4; ++m)
    ta[m] = *(const bf16x8*)&td_lds[((wr << 6) + (m << 4) + (lane & 15)) * 32 + koff8];
#pragma unroll
  for (int n = 0; n < 4; ++n)
    pb4[n] = *(const bf16x8*)&pu_lds[((wc << 6) + (n << 4) + (lane & 15)) * 32 + koff8];

#pragma unroll
  for (int n = 0; n < 4; ++n) {
    int oc = o0 + (wc << 6) + (n << 4) + (lane & 15);
    float bv = bias[oc];
#pragma unroll
    for (int m = 0; m < 4; ++m) {
      floatx4 c;
      c[0] = acc[m][n][0]; c[1] = acc[m][n][1]; c[2] = acc[m][n][2]; c[3] = acc[m][n][3];
      c = __builtin_amdgcn_mfma_f32_16x16x32_bf16(ta[m], pb4[n], c, 0, 0, 0);
#pragma unroll
      for (int r = 0; r < 4; ++r) {
        int tr = t0 + (wr << 6) + (m << 4) + ((lane >> 4) << 2) + r;
        y[(size_t)tr * OUTF + oc] = c[r] + bv;
      }
    }
  }
}

extern "C" void kernel_launch(void* const* d_in, const int* in_sizes, int n_in,
                              void* d_out, int out_size, void* d_ws, size_t ws_size,
                              hipStream_t stream) {
  const float* x      = (const float*)d_in[0];
  const int*   qw     = (const int*)d_in[1];
  const float* wsc    = (const float*)d_in[2];
  const float* smooth = (const float*)d_in[3];
  const float* bias   = (const float*)d_in[4];
  const float* pd     = (const float*)d_in[5];
  const float* pu     = (const float*)d_in[6];
  float* y = (float*)d_out;

  char* ws = (char*)d_ws;
  signed char* qx8 = (signed char*)ws;                            // 33554432 B
  signed char* wq8 = (signed char*)(ws + 33554432);               //  4194304 B
  float* ascales   = (float*)(ws + 33554432 + 4194304);           //  2097152 B
  float* tdown     = (float*)(ws + 33554432 + 4194304 + 2097152); //  2097152 B
  unsigned short* pdT = (unsigned short*)((char*)d_out + (64u << 20));

  unpack_kernel<<<1024, 256, 0, stream>>>(qw, wq8);
  prep_pdT<<<256, 256, 0, stream>>>(pd, pdT);
  quant_kernel<<<TOKENS / 32, 256, 0, stream>>>(x, smooth, pdT, qx8, ascales, tdown);
  gemm_kernel<<<dim3(OUTF / BN, TOKENS / BM), 256, 0, stream>>>(
      qx8, wq8, ascales, wsc, tdown, pu, bias, y);
}